// Round 10
// baseline (441.994 us; speedup 1.0000x reference)
//
#include <hip/hip_runtime.h>
#include <math.h>

// ---------------------------------------------------------------------------
// MultiChannelAttention on MI355X (gfx950)
// out = softmax(causal(rope(xWq^T) rope(xWk^T)^T / sqrt(C))) (xWv^T) Wf^T + b
// B=4 T=2048 C=1024. bf16 MFMA (16x16x32), fp32 accum.
// R18: core4 -> 3-buffer ring (72 KiB, depth-2 prefetch, vmcnt(3) certify)
//      + __launch_bounds__(512,4) => 2 blocks/CU for proj/final (was 1).
//      Same lever that took score 47->~38 (R16: 2->3 blk/CU) and pv
//      46.6->~38 (R17). proj merged back to one z=3 launch (split was
//      diagnostic; fills now mask top-5 anyway).
// R17: pv XCD-paired balanced grid (271.0us). R16: score 3-buf ring +
//      XCD-chunked grid (280.2us). R15: proj split (observability).
// R11: core4 software pipeline (reg-dbuf fragments, counted vmcnt).
// R8: V projection computes Vt natively. R7: triangular score grid.
// R5: native v_sin/v_cos RoPE. R2: fused exp-softmax (P=exp(s), atomics).
// Workspace layout (121 MB):
//   [0,16) xb  [16,24) Wq/Wk/Wv/Wf bf16  [24,40) Q  [40,56) K
//   [56,72) Vt  [72,88) O  [88,120) P bf16  [120,+32K) row_sum
// ---------------------------------------------------------------------------

#define AS1(p) ((__attribute__((address_space(1))) void*)(p))
#define AS3(p) ((__attribute__((address_space(3))) void*)(p))

typedef __attribute__((ext_vector_type(8))) short bf16x8;
typedef __attribute__((ext_vector_type(4))) float f32x4;

__device__ __forceinline__ unsigned short f2bf(float f) {
  unsigned int u = __float_as_uint(f);
  u += 0x7fffu + ((u >> 16) & 1u);   // round-to-nearest-even
  return (unsigned short)(u >> 16);
}

// ---- fp32 -> bf16 cast for x + 4 weight matrices, + rsum zero, one launch -
__global__ __launch_bounds__(256) void cast_all(
    const float* __restrict__ x, const float* __restrict__ Wq,
    const float* __restrict__ Wk, const float* __restrict__ Wv,
    const float* __restrict__ Wf,
    unsigned short* __restrict__ xb, unsigned short* __restrict__ Wqb,
    unsigned short* __restrict__ Wkb, unsigned short* __restrict__ Wvb,
    unsigned short* __restrict__ Wfb, float* __restrict__ rsum) {
  int i = blockIdx.x * 256 + threadIdx.x;           // float4 index
  if (i < 8192) rsum[i] = 0.0f;                     // fused memset (32 KB)
  const float* src; unsigned short* dst; int off;
  if (i < 2097152) { src = x; dst = xb; off = i; }
  else {
    int j = i - 2097152;
    int w = j >> 18; off = j & 262143;              // 262144 float4 per W
    src = (w == 0) ? Wq : (w == 1) ? Wk : (w == 2) ? Wv : Wf;
    dst = (w == 0) ? Wqb : (w == 1) ? Wkb : (w == 2) ? Wvb : Wfb;
  }
  float4 f = ((const float4*)src)[off];
  ushort4 o;
  o.x = f2bf(f.x); o.y = f2bf(f.y); o.z = f2bf(f.z); o.w = f2bf(f.w);
  ((ushort4*)dst)[off] = o;
}

// ---- LDS repack + coalesced bf16x8 store of one mi-slice (256 thr) --------
__device__ __forceinline__ void repack_store_mi(unsigned short (&vals)[4][4],
                                                unsigned short* sh, int mi,
                                                int m0, int n0, long long ldo,
                                                unsigned short* __restrict__ Out) {
  const int tid = threadIdx.x, lane = tid & 63, w = tid >> 6;
  const int half = w & 1, wn = (w >> 1) << 6;
  const int cl = lane & 15, q4 = lane >> 4;
  const int lr = half * 16 + q4 * 4;
#pragma unroll
  for (int ni = 0; ni < 4; ni++)
#pragma unroll
    for (int rr = 0; rr < 4; rr++)
      sh[(lr + rr) * 132 + wn + ni * 16 + cl] = vals[ni][rr];
  __syncthreads();
#pragma unroll
  for (int it = 0; it < 2; ++it) {
    int row = (tid >> 4) + it * 16;          // 0..31
    int c8 = (tid & 15) << 3;                // 0..120
    bf16x8 v = *(const bf16x8*)(sh + row * 132 + c8);
    int gr = m0 + (row < 16 ? mi * 16 + row : 48 + mi * 16 + row);
    *(bf16x8*)(Out + (long long)gr * ldo + n0 + c8) = v;
  }
  __syncthreads();
}

// ---------------------------------------------------------------------------
// core4 (proj/final): 128x256 tile, 512 thr = 8 waves (2M x 4N), per-wave
// 64x64 (acc[4][4]). BK=32; R18: 3 LDS buffers of 24 KiB = 72 KiB
// -> 2 blocks/CU at launch_bounds(512,4). Depth-2 prefetch: stage(kt+2)
// in body, gate vmcnt(3) certifies tile kt+1 (kt+2's 3 loads in flight).
// Reg-dbuf fragments; 2 barriers/K-tile. WAR ledger: stage(kt+2) overwrites
// buf[(kt-1)%3], whose rdfrag(kt-1) reads were consumed by MFMA at iter
// kt-1 before its trailing barrier. 16B chunks swizzled c ^= (row>>1)&3,
// pre-swizzled global source, linear LDS dest. nkt even >= 2.
// ---------------------------------------------------------------------------
__device__ __forceinline__ void core4(
    const unsigned short* __restrict__ A, long long lda,
    const unsigned short* __restrict__ B, long long ldb,
    int nkt, f32x4 (&acc)[4][4], unsigned short* lds) {
  const int tid  = threadIdx.x;
  const int lane = tid & 63;
  const int w    = tid >> 6;
  const int wr   = w >> 2;            // 0..1
  const int wc   = w & 3;             // 0..3
  const int fr   = lane & 15;
  const int fq   = lane >> 4;
  const int csel = (fq ^ ((fr >> 1) & 3)) << 3;   // fragment chunk swizzle
  const int srow = tid >> 2;                      // staging row 0..127
  const int scsw = ((tid & 3) ^ ((srow >> 1) & 3)) << 3;
  const unsigned short* Asrc  = A + (long long)srow * lda + scsw;
  const unsigned short* Bsrc0 = B + (long long)srow * ldb + scsw;
  const unsigned short* Bsrc1 = B + (long long)(srow + 128) * ldb + scsw;
  unsigned short* dsta = lds + tid * 8;           // per-thread 16B slot

  auto stage = [&](int kt) {
    const int bo = (kt % 3) * 12288;
    const long long ko = (long long)kt * 32;
    __builtin_amdgcn_global_load_lds(AS1(Asrc + ko),  AS3(dsta + bo),        16, 0, 0);
    __builtin_amdgcn_global_load_lds(AS1(Bsrc0 + ko), AS3(dsta + bo + 4096), 16, 0, 0);
    __builtin_amdgcn_global_load_lds(AS1(Bsrc1 + ko), AS3(dsta + bo + 8192), 16, 0, 0);
  };
  auto rdfrag = [&](int kt, bf16x8 (&r)[8]) {
    const unsigned short* Ab = lds + (kt % 3) * 12288 + (wr * 64 + fr) * 32 + csel;
    const unsigned short* Bb = lds + (kt % 3) * 12288 + 4096 + (wc * 64 + fr) * 32 + csel;
#pragma unroll
    for (int mi = 0; mi < 4; ++mi) r[mi] = *(const bf16x8*)(Ab + mi * 512);
#pragma unroll
    for (int nj = 0; nj < 4; ++nj) r[4 + nj] = *(const bf16x8*)(Bb + nj * 512);
  };

  bf16x8 ra[8], rb[8];
  stage(0); stage(1);
  asm volatile("s_waitcnt vmcnt(3)" ::: "memory");   // tile 0 landed
  __builtin_amdgcn_s_barrier();
  rdfrag(0, ra);

  auto body = [&](int kt, bf16x8 (&cur)[8], bf16x8 (&nxt)[8]) {
    if (kt + 2 < nkt) {
      stage(kt + 2);
      asm volatile("s_waitcnt vmcnt(3)" ::: "memory");   // tile kt+1 landed
    } else if (kt + 1 < nkt) {
      asm volatile("s_waitcnt vmcnt(0)" ::: "memory");
    }
    if (kt + 1 < nkt) {
      __builtin_amdgcn_s_barrier();
      rdfrag(kt + 1, nxt);
    }
    __builtin_amdgcn_s_setprio(1);
#pragma unroll
    for (int mi = 0; mi < 4; ++mi)
#pragma unroll
      for (int nj = 0; nj < 4; ++nj)
        acc[mi][nj] = __builtin_amdgcn_mfma_f32_16x16x32_bf16(cur[mi], cur[4 + nj], acc[mi][nj], 0, 0, 0);
    __builtin_amdgcn_s_setprio(0);
    if (kt + 1 < nkt) __builtin_amdgcn_s_barrier();
  };

#pragma unroll 1
  for (int kt = 0; kt < nkt; kt += 2) {
    body(kt, ra, rb);
    body(kt + 1, rb, ra);
  }
}

// ---------------------------------------------------------------------------
// core4h (score/pv): 256 thr / 128x128 tile, 4 waves (2M x 2N), per-wave
// 64x64 (acc[4][4]). BK=32; 3 LDS buffers of 16 KiB = 48 KiB -> 3 blocks/CU.
// Depth-2 prefetch: stage(kt+2) in body, gate vmcnt(4) certifies tile kt+1.
// Reg-dbuf fragments; 2 barriers/K-tile. nkt even >= 2.
// ---------------------------------------------------------------------------
__device__ __forceinline__ void core4h(
    const unsigned short* __restrict__ A, long long lda,
    const unsigned short* __restrict__ B, long long ldb,
    int nkt, f32x4 (&acc)[4][4], unsigned short* lds) {
  const int tid  = threadIdx.x;          // 0..255
  const int lane = tid & 63;
  const int w    = tid >> 6;             // 0..3
  const int wm   = (w & 1) << 6;         // M half
  const int wn   = (w >> 1) << 6;        // N half
  const int fr   = lane & 15;
  const int fq   = lane >> 4;
  const int csel = (fq ^ ((fr >> 1) & 3)) << 3;
  const int srow = tid >> 2;             // 0..63
  const int scsw = ((tid & 3) ^ ((srow >> 1) & 3)) << 3;
  const unsigned short* Asrc0 = A + (long long)srow * lda + scsw;
  const unsigned short* Asrc1 = A + (long long)(srow + 64) * lda + scsw;
  const unsigned short* Bsrc0 = B + (long long)srow * ldb + scsw;
  const unsigned short* Bsrc1 = B + (long long)(srow + 64) * ldb + scsw;
  unsigned short* dsta = lds + tid * 8;  // 16B per thread per instr

  auto stage = [&](int kt) {
    const int bo = (kt % 3) * 8192;
    const long long ko = (long long)kt * 32;
    __builtin_amdgcn_global_load_lds(AS1(Asrc0 + ko), AS3(dsta + bo),        16, 0, 0);
    __builtin_amdgcn_global_load_lds(AS1(Asrc1 + ko), AS3(dsta + bo + 2048), 16, 0, 0);
    __builtin_amdgcn_global_load_lds(AS1(Bsrc0 + ko), AS3(dsta + bo + 4096), 16, 0, 0);
    __builtin_amdgcn_global_load_lds(AS1(Bsrc1 + ko), AS3(dsta + bo + 6144), 16, 0, 0);
  };
  auto rdfrag = [&](int kt, bf16x8 (&r)[8]) {
    const unsigned short* Ab = lds + (kt % 3) * 8192 + (wm + fr) * 32 + csel;
    const unsigned short* Bb = lds + (kt % 3) * 8192 + 4096 + (wn + fr) * 32 + csel;
#pragma unroll
    for (int mi = 0; mi < 4; ++mi) r[mi] = *(const bf16x8*)(Ab + mi * 512);
#pragma unroll
    for (int nj = 0; nj < 4; ++nj) r[4 + nj] = *(const bf16x8*)(Bb + nj * 512);
  };

  bf16x8 ra[8], rb[8];
  stage(0); stage(1);
  asm volatile("s_waitcnt vmcnt(4)" ::: "memory");   // tile 0 landed
  __builtin_amdgcn_s_barrier();
  rdfrag(0, ra);

  auto body = [&](int kt, bf16x8 (&cur)[8], bf16x8 (&nxt)[8]) {
    if (kt + 2 < nkt) {
      stage(kt + 2);
      asm volatile("s_waitcnt vmcnt(4)" ::: "memory");   // tile kt+1 landed
    } else if (kt + 1 < nkt) {
      asm volatile("s_waitcnt vmcnt(0)" ::: "memory");
    }
    if (kt + 1 < nkt) {
      __builtin_amdgcn_s_barrier();
      rdfrag(kt + 1, nxt);
    }
    __builtin_amdgcn_s_setprio(1);
#pragma unroll
    for (int mi = 0; mi < 4; ++mi)
#pragma unroll
      for (int nj = 0; nj < 4; ++nj)
        acc[mi][nj] = __builtin_amdgcn_mfma_f32_16x16x32_bf16(cur[mi], cur[4 + nj], acc[mi][nj], 0, 0, 0);
    __builtin_amdgcn_s_setprio(0);
    if (kt + 1 < nkt) __builtin_amdgcn_s_barrier();
  };

#pragma unroll 1
  for (int kt = 0; kt < nkt; kt += 2) {
    body(kt, ra, rb);
    body(kt + 1, rb, ra);
  }
}

// ---- Q/K/V projections; Q/K get RoPE; V computed AS Vt (swapped operands) -
// Grid (64, 4, 3), 512 threads, 2 blocks/CU (72 KiB LDS).
__global__ __launch_bounds__(512, 4) void proj_rope(
    const unsigned short* __restrict__ xb,
    const unsigned short* __restrict__ Wq, const unsigned short* __restrict__ Wk,
    const unsigned short* __restrict__ Wv,
    const float* __restrict__ bq, const float* __restrict__ bk, const float* __restrict__ bv,
    unsigned short* __restrict__ Q, unsigned short* __restrict__ Ko,
    unsigned short* __restrict__ Vt) {
  __shared__ unsigned short lds[36864];   // 72 KiB: GEMM 3-buf, then repack
  const int which = blockIdx.z;
  const int tid = threadIdx.x, lane = tid & 63, w = tid >> 6;
  const int wr = w >> 2, wc = w & 3;
  const int cl = lane & 15, q4 = lane >> 4;

  f32x4 acc[4][4];
#pragma unroll
  for (int i = 0; i < 4; i++)
#pragma unroll
    for (int j = 0; j < 4; j++)
#pragma unroll
      for (int k = 0; k < 4; k++) acc[i][j][k] = 0.0f;

  if (which == 2) {
    // ---- V path: Vt[d,s] = sum_k Wv[d,k] x[s,k]; A = Wv (m=d), B = x (n=s)
    const int p = blockIdx.x + 64 * blockIdx.y;     // physical 0..255
    const int m0 = ((p >> 3) & 7) * 128;            // d tile
    const int n0 = (4 * (p & 7) + (p >> 6)) * 256;  // global s tile (XCD remap)
    core4(Wv + (long long)m0 * 1024, 1024, xb + (long long)n0 * 1024, 1024, 32, acc, lds);
    __syncthreads();
    const int b = n0 >> 11, sloc = n0 & 2047;
#pragma unroll
    for (int mi = 0; mi < 4; ++mi) {
      const int lr = wr * 64 + mi * 16 + q4 * 4;
#pragma unroll
      for (int rr = 0; rr < 4; ++rr) {
        const float b_ = bv[m0 + lr + rr];          // bias per d-row
#pragma unroll
        for (int nj = 0; nj < 4; ++nj)
          lds[(lr + rr) * 264 + wc * 64 + nj * 16 + cl] = f2bf(acc[mi][nj][rr] + b_);
      }
    }
    __syncthreads();
    unsigned short* Outb = Vt + (long long)b * 1024 * 2048;
#pragma unroll
    for (int it = 0; it < 8; ++it) {
      int c = it * 512 + tid;
      int row = c >> 5, c8 = (c & 31) << 3;
      bf16x8 v = *(const bf16x8*)(lds + row * 264 + c8);
      *(bf16x8*)(Outb + (long long)(m0 + row) * 2048 + sloc + c8) = v;
    }
    return;
  }

  // ---- Q/K path: bias + RoPE (native sin/cos) ----
  const int m0 = blockIdx.x * 128;    // token rows
  const int n0 = blockIdx.y * 256;    // feature cols
  const unsigned short* W = which == 0 ? Wq : Wk;
  const float* bias = which == 0 ? bq : bk;
  unsigned short* Out = which == 0 ? Q : Ko;

  core4(xb + (long long)m0 * 1024, 1024, W + (long long)n0 * 1024, 1024, 32, acc, lds);
  __syncthreads();

  const float NEG_L2T_512 = -0.025952563239354392f;  // -log2(10000)/512
  const float INV2PI = 0.15915494309189535f;
  float freqn[4];
#pragma unroll
  for (int nj = 0; nj < 4; ++nj) {
    int gn = n0 + wc * 64 + nj * 16 + cl;
    freqn[nj] = exp2f(NEG_L2T_512 * (float)(gn >> 1));
  }
#pragma unroll
  for (int mi = 0; mi < 4; ++mi) {
    const int lr = wr * 64 + mi * 16 + q4 * 4;
    const int t0 = (m0 & 2047) + lr;   // batch-local time (tiles never straddle)
#pragma unroll
    for (int nj = 0; nj < 4; ++nj) {
      const int gn = n0 + wc * 64 + nj * 16 + cl;
      const float bi = bias[gn];
#pragma unroll
      for (int rr = 0; rr < 4; ++rr) {
        float v = acc[mi][nj][rr] + bi;
        float partner = __shfl_xor(v, 1, 64);
        float ang = (float)(t0 + rr) * freqn[nj];
        float rev = ang * INV2PI;
        rev = rev - floorf(rev);           // v_sin/v_cos domain
        float c_ = __builtin_amdgcn_cosf(rev);
        float s_ = __builtin_amdgcn_sinf(rev);
        v = v * c_ + ((gn & 1) ? partner : -partner) * s_;
        lds[(lr + rr) * 264 + wc * 64 + nj * 16 + cl] = f2bf(v);
      }
    }
  }
  __syncthreads();
#pragma unroll
  for (int it = 0; it < 8; ++it) {
    int c = it * 512 + tid;
    int row = c >> 5, c8 = (c & 31) << 3;
    bf16x8 v = *(const bf16x8*)(lds + row * 264 + c8);
    *(bf16x8*)(Out + (long long)(m0 + row) * 1024 + n0 + c8) = v;
  }
}

// ---- P = exp(Q K^T / sqrt(C)) (causal-zeroed), bf16; row sums via atomics -
// Flat 544-block grid, XCD-chunked bijective remap (544 = 8*68).
__global__ __launch_bounds__(256, 2) void score_exp(const unsigned short* __restrict__ Q,
                                                    const unsigned short* __restrict__ Kk,
                                                    unsigned short* __restrict__ P,
                                                    float* __restrict__ row_sum) {
  __shared__ unsigned short sh[24576];   // 48 KiB: 3 GEMM bufs, then repack
  const int flat = blockIdx.x;                       // 0..543
  const int swz = (flat & 7) * 68 + (flat >> 3);     // bijective XCD chunking
  const int b = swz / 136;
  const int bx = swz % 136;
  int i = (int)((sqrtf(8.0f * (float)bx + 1.0f) - 1.0f) * 0.5f);
  while ((i + 1) * (i + 2) / 2 <= bx) ++i;
  while (i * (i + 1) / 2 > bx) --i;
  const int j = bx - i * (i + 1) / 2;       // 0..i
  const int m0 = i * 128, n0 = j * 128;
  const unsigned short* Qb = Q + (long long)b * 2048 * 1024;
  const unsigned short* Kb = Kk + (long long)b * 2048 * 1024;
  unsigned short* Pb = P + (long long)b * 2048 * 2048;
  float* rs = row_sum + b * 2048;

  f32x4 acc[4][4];
#pragma unroll
  for (int ii = 0; ii < 4; ii++)
#pragma unroll
    for (int jj = 0; jj < 4; jj++)
#pragma unroll
      for (int k = 0; k < 4; k++) acc[ii][jj][k] = 0.0f;

  core4h(Qb + (long long)m0 * 1024, 1024, Kb + (long long)n0 * 1024, 1024, 32, acc, sh);
  __syncthreads();

  const int tid = threadIdx.x, lane = tid & 63, w = tid >> 6;
  const int wm = (w & 1) << 6, wn = (w >> 1) << 6;
  const int cl = lane & 15, q4 = lane >> 4;
  const bool diag = (i == j);
#pragma unroll
  for (int mi = 0; mi < 4; mi++) {
    unsigned short vals[4][4];
    float rsum[4] = {0.f, 0.f, 0.f, 0.f};
#pragma unroll
    for (int ni = 0; ni < 4; ni++) {
      const int gn = n0 + wn + ni * 16 + cl;
#pragma unroll
      for (int rr = 0; rr < 4; rr++) {
        const int gm = m0 + wm + mi * 16 + q4 * 4 + rr;
        float e = (diag && gn > gm) ? 0.0f : __expf(acc[mi][ni][rr] * 0.03125f);
        vals[ni][rr] = f2bf(e);
        rsum[rr] += e;
      }
    }
#pragma unroll
    for (int rr = 0; rr < 4; rr++) {
#pragma unroll
      for (int off = 1; off < 16; off <<= 1) rsum[rr] += __shfl_xor(rsum[rr], off, 64);
    }
    if (cl == 0) {
      const int gm = m0 + wm + mi * 16 + q4 * 4;
#pragma unroll
      for (int rr = 0; rr < 4; rr++) atomicAdd(&rs[gm + rr], rsum[rr]);
    }
    repack_store_mi(vals, sh, mi, m0, n0, 2048, Pb);
  }
}

// ---- O = (P V) / row_sum -------------------------------------------------
// Flat 512-block grid, XCD-paired balanced decode (R17).
__global__ __launch_bounds__(256, 2) void pv_gemm(const unsigned short* __restrict__ P,
                                                  const unsigned short* __restrict__ Vt,
                                                  const float* __restrict__ row_sum,
                                                  unsigned short* __restrict__ O) {
  __shared__ unsigned short sh[24576];   // 48 KiB: 3 GEMM bufs, then repack
  const int p = blockIdx.x;          // 0..511
  const int xcd = p & 7;
  const int idx = p >> 3;            // 0..63
  const int g = idx >> 3;            // 0..7 (4 long groups, then 4 short)
  const int dt = idx & 7;            // d tile
  const int b  = (g < 4) ? g : g - 4;
  const int mt = (g < 4) ? 15 - xcd : xcd;
  const int m0 = mt * 128;           // t tile
  const int n0 = dt * 128;           // d tile
  const unsigned short* Pb = P + (long long)b * 2048 * 2048;
  const unsigned short* Vb = Vt + (long long)b * 1024 * 2048;
  const float* rs = row_sum + b * 2048;
  const int nkt = 4 * (mt + 1);      // K = m0+128 -> K/32, even >= 4

  f32x4 acc[4][4];
#pragma unroll
  for (int i = 0; i < 4; i++)
#pragma unroll
    for (int j = 0; j < 4; j++)
#pragma unroll
      for (int k = 0; k < 4; k++) acc[i][j][k] = 0.0f;

  core4h(Pb + (long long)m0 * 2048, 2048, Vb + (long long)n0 * 2048, 2048, nkt, acc, sh);
  __syncthreads();

  const int tid = threadIdx.x, lane = tid & 63, w = tid >> 6;
  const int wm = (w & 1) << 6;
  const int q4 = lane >> 4;
#pragma unroll
  for (int mi = 0; mi < 4; mi++) {
    unsigned short vals[4][4];
    float inv[4];
    const int gm0 = m0 + wm + mi * 16 + q4 * 4;
#pragma unroll
    for (int rr = 0; rr < 4; rr++) inv[rr] = 1.0f / rs[gm0 + rr];
#pragma unroll
    for (int ni = 0; ni < 4; ni++)
#pragma unroll
      for (int rr = 0; rr < 4; rr++)
        vals[ni][rr] = f2bf(acc[mi][ni][rr] * inv[rr]);
    repack_store_mi(vals, sh, mi, m0, n0, 1024, O + (long long)b * 2048 * 1024);
  }
}

// ---- out = O Wf^T + bf, fp32 out (core4, 512 thr, 2 blk/CU) ---------------
__global__ __launch_bounds__(512, 4) void final_gemm(const unsigned short* __restrict__ O,
                                                     const unsigned short* __restrict__ Wf,
                                                     const float* __restrict__ bf_,
                                                     float* __restrict__ out) {
  __shared__ unsigned short lds[36864];   // 72 KiB: GEMM 3-buf, then repack
  float* shf = (float*)lds;
  const int tid = threadIdx.x, lane = tid & 63, w = tid >> 6;
  const int wr = w >> 2, wc = w & 3;
  const int cl = lane & 15, q4 = lane >> 4;
  const int m0 = blockIdx.x * 128;
  const int n0 = blockIdx.y * 256;

  f32x4 acc[4][4];
#pragma unroll
  for (int i = 0; i < 4; i++)
#pragma unroll
    for (int j = 0; j < 4; j++)
#pragma unroll
      for (int k = 0; k < 4; k++) acc[i][j][k] = 0.0f;

  core4(O + (long long)m0 * 1024, 1024, Wf + (long long)n0 * 1024, 1024, 32, acc, lds);

  // fp32 repack in two 64-row rounds (64 x 260 floats = 65 KiB <= 72 KiB)
#pragma unroll
  for (int r = 0; r < 2; ++r) {
    __syncthreads();
    if (wr == r) {
#pragma unroll
      for (int mi = 0; mi < 4; ++mi)
#pragma unroll
        for (int nj = 0; nj < 4; ++nj) {
          const int col = wc * 64 + nj * 16 + cl;
          const float bi = bf_[n0 + col];
#pragma unroll
          for (int rr = 0; rr < 4; ++rr)
            shf[(mi * 16 + q4 * 4 + rr) * 260 + col] = acc[mi][nj][rr] + bi;
        }
    }
    __syncthreads();
#pragma unroll
    for (int it = 0; it < 8; ++it) {
      int c = it * 512 + tid;
      int row = c >> 6, c4 = (c & 63) << 2;
      float4 v = *(const float4*)(shf + row * 260 + c4);
      *(float4*)(out + (long long)(m0 + r * 64 + row) * 1024 + n0 + c4) = v;
    }
  }
}

// ---------------------------------------------------------------------------
extern "C" void kernel_launch(void* const* d_in, const int* in_sizes, int n_in,
                              void* d_out, int out_size, void* d_ws, size_t ws_size,
                              hipStream_t stream) {
  (void)in_sizes; (void)n_in; (void)out_size; (void)ws_size;
  const float* x   = (const float*)d_in[0];
  const float* Wq  = (const float*)d_in[1];
  const float* bq  = (const float*)d_in[2];
  const float* Wk  = (const float*)d_in[3];
  const float* bk  = (const float*)d_in[4];
  const float* Wv  = (const float*)d_in[5];
  const float* bv  = (const float*)d_in[6];
  const float* Wf  = (const float*)d_in[7];
  const float* bf_ = (const float*)d_in[8];
  float* out = (float*)d_out;

  char* ws = (char*)d_ws;
  const size_t MB = 1024 * 1024;
  unsigned short* xb  = (unsigned short*)(ws);             // 16 MB
  unsigned short* Wqb = (unsigned short*)(ws + 16 * MB);   // 2 MB
  unsigned short* Wkb = (unsigned short*)(ws + 18 * MB);   // 2 MB
  unsigned short* Wvb = (unsigned short*)(ws + 20 * MB);   // 2 MB
  unsigned short* Wfb = (unsigned short*)(ws + 22 * MB);   // 2 MB
  unsigned short* Qb  = (unsigned short*)(ws + 24 * MB);   // 16 MB
  unsigned short* Kb  = (unsigned short*)(ws + 40 * MB);   // 16 MB
  unsigned short* Vtb = (unsigned short*)(ws + 56 * MB);   // 16 MB
  unsigned short* Ob  = (unsigned short*)(ws + 72 * MB);   // 16 MB
  unsigned short* Pb  = (unsigned short*)(ws + 88 * MB);   // 32 MB P bf16
  float*          rsum= (float*)(ws + 120 * MB);           // 32 KB row sums

  cast_all<<<dim3(3145728 / 256), dim3(256), 0, stream>>>(x, Wq, Wk, Wv, Wf, xb, Wqb, Wkb, Wvb, Wfb, rsum);
  proj_rope<<<dim3(64, 4, 3), dim3(512), 0, stream>>>(xb, Wqb, Wkb, Wvb, bq, bk, bv, Qb, Kb, Vtb);
  score_exp<<<dim3(544), dim3(256), 0, stream>>>(Qb, Kb, Pb, rsum);
  pv_gemm<<<dim3(512), dim3(256), 0, stream>>>(Pb, Vtb, rsum, Ob);
  final_gemm<<<dim3(64, 4), dim3(512), 0, stream>>>(Ob, Wfb, bf_, out);
}

// Round 11
// 275.845 us; speedup vs baseline: 1.6023x; 1.6023x over previous
//
#include <hip/hip_runtime.h>
#include <math.h>

// ---------------------------------------------------------------------------
// MultiChannelAttention on MI355X (gfx950)
// out = softmax(causal(rope(xWq^T) rope(xWk^T)^T / sqrt(C))) (xWv^T) Wf^T + b
// B=4 T=2048 C=1024. bf16 MFMA (16x16x32), fp32 accum.
// R19: R18's launch_bounds(512,4) spilled acc to scratch (VGPR cap 128 <
//      ~152 needed; WRITE_SIZE 49->413MB, proj 220us). Full revert to R17
//      (271.0us measured) + proj moved onto core4h (256thr/128x128/48KiB
//      ring -> 3 blk/CU, no spill at 170-reg cap) with flat 1536-block
//      XCD-chunked grid (8x192, n-fast so same-XCD blocks share x-panels,
//      W L2-resident). Epilogues are the original R8 256-thread RoPE/V
//      repack code. Same lever that fixed score (R16) and pv (R17).
// R17: pv XCD-paired balanced grid (271.0us). R16: score 3-buf ring +
//      XCD-chunked grid (280.2us). R11: core4 pipeline (reg-dbuf, counted
//      vmcnt). R8: V projection computes Vt natively. R5: native RoPE.
//      R2: fused exp-softmax (P=exp(s), atomic row sums).
// Workspace layout (121 MB):
//   [0,16) xb  [16,24) Wq/Wk/Wv/Wf bf16  [24,40) Q  [40,56) K
//   [56,72) Vt  [72,88) O  [88,120) P bf16  [120,+32K) row_sum
// ---------------------------------------------------------------------------

#define AS1(p) ((__attribute__((address_space(1))) void*)(p))
#define AS3(p) ((__attribute__((address_space(3))) void*)(p))

typedef __attribute__((ext_vector_type(8))) short bf16x8;
typedef __attribute__((ext_vector_type(4))) float f32x4;

__device__ __forceinline__ unsigned short f2bf(float f) {
  unsigned int u = __float_as_uint(f);
  u += 0x7fffu + ((u >> 16) & 1u);   // round-to-nearest-even
  return (unsigned short)(u >> 16);
}

// ---- fp32 -> bf16 cast for x + 4 weight matrices, + rsum zero, one launch -
__global__ __launch_bounds__(256) void cast_all(
    const float* __restrict__ x, const float* __restrict__ Wq,
    const float* __restrict__ Wk, const float* __restrict__ Wv,
    const float* __restrict__ Wf,
    unsigned short* __restrict__ xb, unsigned short* __restrict__ Wqb,
    unsigned short* __restrict__ Wkb, unsigned short* __restrict__ Wvb,
    unsigned short* __restrict__ Wfb, float* __restrict__ rsum) {
  int i = blockIdx.x * 256 + threadIdx.x;           // float4 index
  if (i < 8192) rsum[i] = 0.0f;                     // fused memset (32 KB)
  const float* src; unsigned short* dst; int off;
  if (i < 2097152) { src = x; dst = xb; off = i; }
  else {
    int j = i - 2097152;
    int w = j >> 18; off = j & 262143;              // 262144 float4 per W
    src = (w == 0) ? Wq : (w == 1) ? Wk : (w == 2) ? Wv : Wf;
    dst = (w == 0) ? Wqb : (w == 1) ? Wkb : (w == 2) ? Wvb : Wfb;
  }
  float4 f = ((const float4*)src)[off];
  ushort4 o;
  o.x = f2bf(f.x); o.y = f2bf(f.y); o.z = f2bf(f.z); o.w = f2bf(f.w);
  ((ushort4*)dst)[off] = o;
}

// ---- LDS repack + coalesced bf16x8 store of one mi-slice (256 thr) --------
__device__ __forceinline__ void repack_store_mi(unsigned short (&vals)[4][4],
                                                unsigned short* sh, int mi,
                                                int m0, int n0, long long ldo,
                                                unsigned short* __restrict__ Out) {
  const int tid = threadIdx.x, lane = tid & 63, w = tid >> 6;
  const int half = w & 1, wn = (w >> 1) << 6;
  const int cl = lane & 15, q4 = lane >> 4;
  const int lr = half * 16 + q4 * 4;
#pragma unroll
  for (int ni = 0; ni < 4; ni++)
#pragma unroll
    for (int rr = 0; rr < 4; rr++)
      sh[(lr + rr) * 132 + wn + ni * 16 + cl] = vals[ni][rr];
  __syncthreads();
#pragma unroll
  for (int it = 0; it < 2; ++it) {
    int row = (tid >> 4) + it * 16;          // 0..31
    int c8 = (tid & 15) << 3;                // 0..120
    bf16x8 v = *(const bf16x8*)(sh + row * 132 + c8);
    int gr = m0 + (row < 16 ? mi * 16 + row : 48 + mi * 16 + row);
    *(bf16x8*)(Out + (long long)gr * ldo + n0 + c8) = v;
  }
  __syncthreads();
}

// ---------------------------------------------------------------------------
// core4 (final_gemm): 128x256 tile, 512 thr = 8 waves (2M x 4N), per-wave
// 64x64 (acc[4][4]). BK=32; 4 LDS buffers of 24 KiB; 3-deep global prefetch
// (vmcnt(6) certify); reg-dbuf fragments. 2 barriers/K-tile. 16B chunks
// swizzled c ^= (row>>1)&3, pre-swizzled global source, linear LDS dest.
// C[m,n] = sum_k A[m,k]*B[n,k], A/B bf16 K-fast. nkt even >= 4.
// ---------------------------------------------------------------------------
__device__ __forceinline__ void core4(
    const unsigned short* __restrict__ A, long long lda,
    const unsigned short* __restrict__ B, long long ldb,
    int nkt, f32x4 (&acc)[4][4], unsigned short* lds) {
  const int tid  = threadIdx.x;
  const int lane = tid & 63;
  const int w    = tid >> 6;
  const int wr   = w >> 2;            // 0..1
  const int wc   = w & 3;             // 0..3
  const int fr   = lane & 15;
  const int fq   = lane >> 4;
  const int csel = (fq ^ ((fr >> 1) & 3)) << 3;   // fragment chunk swizzle
  const int srow = tid >> 2;                      // staging row 0..127
  const int scsw = ((tid & 3) ^ ((srow >> 1) & 3)) << 3;
  const unsigned short* Asrc  = A + (long long)srow * lda + scsw;
  const unsigned short* Bsrc0 = B + (long long)srow * ldb + scsw;
  const unsigned short* Bsrc1 = B + (long long)(srow + 128) * ldb + scsw;
  unsigned short* dsta = lds + tid * 8;           // per-thread 16B slot

  auto stage = [&](int kt) {
    const int bo = (kt & 3) * 12288;
    const long long ko = (long long)kt * 32;
    __builtin_amdgcn_global_load_lds(AS1(Asrc + ko),  AS3(dsta + bo),        16, 0, 0);
    __builtin_amdgcn_global_load_lds(AS1(Bsrc0 + ko), AS3(dsta + bo + 4096), 16, 0, 0);
    __builtin_amdgcn_global_load_lds(AS1(Bsrc1 + ko), AS3(dsta + bo + 8192), 16, 0, 0);
  };
  auto rdfrag = [&](int kt, bf16x8 (&r)[8]) {
    const unsigned short* Ab = lds + (kt & 3) * 12288 + (wr * 64 + fr) * 32 + csel;
    const unsigned short* Bb = lds + (kt & 3) * 12288 + 4096 + (wc * 64 + fr) * 32 + csel;
#pragma unroll
    for (int mi = 0; mi < 4; ++mi) r[mi] = *(const bf16x8*)(Ab + mi * 512);
#pragma unroll
    for (int nj = 0; nj < 4; ++nj) r[4 + nj] = *(const bf16x8*)(Bb + nj * 512);
  };

  bf16x8 ra[8], rb[8];
  stage(0); stage(1); stage(2);
  asm volatile("s_waitcnt vmcnt(6)" ::: "memory");
  __builtin_amdgcn_s_barrier();
  rdfrag(0, ra);

  auto body = [&](int kt, bf16x8 (&cur)[8], bf16x8 (&nxt)[8]) {
    if (kt + 3 < nkt) {
      stage(kt + 3);
      asm volatile("s_waitcnt vmcnt(6)" ::: "memory");
    } else if (kt + 2 < nkt) {
      asm volatile("s_waitcnt vmcnt(3)" ::: "memory");
    } else if (kt + 1 < nkt) {
      asm volatile("s_waitcnt vmcnt(0)" ::: "memory");
    }
    if (kt + 1 < nkt) {
      __builtin_amdgcn_s_barrier();
      rdfrag(kt + 1, nxt);
    }
    __builtin_amdgcn_s_setprio(1);
#pragma unroll
    for (int mi = 0; mi < 4; ++mi)
#pragma unroll
      for (int nj = 0; nj < 4; ++nj)
        acc[mi][nj] = __builtin_amdgcn_mfma_f32_16x16x32_bf16(cur[mi], cur[4 + nj], acc[mi][nj], 0, 0, 0);
    __builtin_amdgcn_s_setprio(0);
    if (kt + 1 < nkt) __builtin_amdgcn_s_barrier();
  };

#pragma unroll 1
  for (int kt = 0; kt < nkt; kt += 2) {
    body(kt, ra, rb);
    body(kt + 1, rb, ra);
  }
}

// ---------------------------------------------------------------------------
// core4h (proj/score/pv): 256 thr / 128x128 tile, 4 waves (2M x 2N), per-wave
// 64x64 (acc[4][4]). BK=32; 3 LDS buffers of 16 KiB = 48 KiB -> 3 blocks/CU.
// Depth-2 prefetch: stage(kt+2) in body, gate vmcnt(4) certifies tile kt+1.
// Reg-dbuf fragments; 2 barriers/K-tile. WAR ledger: stage(kt+2) overwrites
// buf[(kt-1)%3], whose rdfrag(kt-1) reads were consumed by MFMA at iter kt-1
// before its trailing barrier. nkt even >= 2.
// ---------------------------------------------------------------------------
__device__ __forceinline__ void core4h(
    const unsigned short* __restrict__ A, long long lda,
    const unsigned short* __restrict__ B, long long ldb,
    int nkt, f32x4 (&acc)[4][4], unsigned short* lds) {
  const int tid  = threadIdx.x;          // 0..255
  const int lane = tid & 63;
  const int w    = tid >> 6;             // 0..3
  const int wm   = (w & 1) << 6;         // M half
  const int wn   = (w >> 1) << 6;        // N half
  const int fr   = lane & 15;
  const int fq   = lane >> 4;
  const int csel = (fq ^ ((fr >> 1) & 3)) << 3;
  const int srow = tid >> 2;             // 0..63
  const int scsw = ((tid & 3) ^ ((srow >> 1) & 3)) << 3;
  const unsigned short* Asrc0 = A + (long long)srow * lda + scsw;
  const unsigned short* Asrc1 = A + (long long)(srow + 64) * lda + scsw;
  const unsigned short* Bsrc0 = B + (long long)srow * ldb + scsw;
  const unsigned short* Bsrc1 = B + (long long)(srow + 64) * ldb + scsw;
  unsigned short* dsta = lds + tid * 8;  // 16B per thread per instr

  auto stage = [&](int kt) {
    const int bo = (kt % 3) * 8192;
    const long long ko = (long long)kt * 32;
    __builtin_amdgcn_global_load_lds(AS1(Asrc0 + ko), AS3(dsta + bo),        16, 0, 0);
    __builtin_amdgcn_global_load_lds(AS1(Asrc1 + ko), AS3(dsta + bo + 2048), 16, 0, 0);
    __builtin_amdgcn_global_load_lds(AS1(Bsrc0 + ko), AS3(dsta + bo + 4096), 16, 0, 0);
    __builtin_amdgcn_global_load_lds(AS1(Bsrc1 + ko), AS3(dsta + bo + 6144), 16, 0, 0);
  };
  auto rdfrag = [&](int kt, bf16x8 (&r)[8]) {
    const unsigned short* Ab = lds + (kt % 3) * 8192 + (wm + fr) * 32 + csel;
    const unsigned short* Bb = lds + (kt % 3) * 8192 + 4096 + (wn + fr) * 32 + csel;
#pragma unroll
    for (int mi = 0; mi < 4; ++mi) r[mi] = *(const bf16x8*)(Ab + mi * 512);
#pragma unroll
    for (int nj = 0; nj < 4; ++nj) r[4 + nj] = *(const bf16x8*)(Bb + nj * 512);
  };

  bf16x8 ra[8], rb[8];
  stage(0); stage(1);
  asm volatile("s_waitcnt vmcnt(4)" ::: "memory");   // tile 0 landed
  __builtin_amdgcn_s_barrier();
  rdfrag(0, ra);

  auto body = [&](int kt, bf16x8 (&cur)[8], bf16x8 (&nxt)[8]) {
    if (kt + 2 < nkt) {
      stage(kt + 2);
      asm volatile("s_waitcnt vmcnt(4)" ::: "memory");   // tile kt+1 landed
    } else if (kt + 1 < nkt) {
      asm volatile("s_waitcnt vmcnt(0)" ::: "memory");
    }
    if (kt + 1 < nkt) {
      __builtin_amdgcn_s_barrier();
      rdfrag(kt + 1, nxt);
    }
    __builtin_amdgcn_s_setprio(1);
#pragma unroll
    for (int mi = 0; mi < 4; ++mi)
#pragma unroll
      for (int nj = 0; nj < 4; ++nj)
        acc[mi][nj] = __builtin_amdgcn_mfma_f32_16x16x32_bf16(cur[mi], cur[4 + nj], acc[mi][nj], 0, 0, 0);
    __builtin_amdgcn_s_setprio(0);
    if (kt + 1 < nkt) __builtin_amdgcn_s_barrier();
  };

#pragma unroll 1
  for (int kt = 0; kt < nkt; kt += 2) {
    body(kt, ra, rb);
    body(kt + 1, rb, ra);
  }
}

// ---- Q/K/V projections on core4h (R19); Q/K get RoPE; V computed AS Vt ----
// Flat grid 1536 = 8*192, XCD-chunked bijective remap. which = swz>>9;
// t = swz&511. Q/K: m0=(t>>3)*128 tokens, n0=(t&7)*128 features (n-fast:
// 8 consecutive same-XCD blocks share one x-panel; W stays L2-resident).
// V: d0=(t&7)*128, s0=(t>>3)*128. 3 blocks/CU (48 KiB ring), 2 exact rounds.
__global__ __launch_bounds__(256, 2) void proj_rope(
    const unsigned short* __restrict__ xb,
    const unsigned short* __restrict__ Wq, const unsigned short* __restrict__ Wk,
    const unsigned short* __restrict__ Wv,
    const float* __restrict__ bq, const float* __restrict__ bk, const float* __restrict__ bv,
    unsigned short* __restrict__ Q, unsigned short* __restrict__ Ko,
    unsigned short* __restrict__ Vt) {
  __shared__ unsigned short sh[24576];   // 48 KiB: 3 GEMM bufs, then repack
  const int flat = blockIdx.x;                     // 0..1535
  const int swz = (flat & 7) * 192 + (flat >> 3);  // bijective XCD chunking
  const int which = swz >> 9;                      // 0 Q, 1 K, 2 V
  const int t = swz & 511;
  const int tid = threadIdx.x, lane = tid & 63, w = tid >> 6;
  const int wm = (w & 1) << 6, wn = (w >> 1) << 6;
  const int cl = lane & 15, q4 = lane >> 4;

  f32x4 acc[4][4];
#pragma unroll
  for (int i = 0; i < 4; i++)
#pragma unroll
    for (int j = 0; j < 4; j++)
#pragma unroll
      for (int k = 0; k < 4; k++) acc[i][j][k] = 0.0f;

  if (which == 2) {
    // ---- V path: Vt[d,s] = sum_k Wv[d,k] x[s,k]; A = Wv (m=d), B = x (n=s)
    const int d0 = (t & 7) * 128;
    const int s0 = (t >> 3) * 128;                 // global token col
    core4h(Wv + (long long)d0 * 1024, 1024, xb + (long long)s0 * 1024, 1024, 32, acc, sh);
    __syncthreads();
    const int b = s0 >> 11, sloc = s0 & 2047;
    unsigned short* Outb = Vt + (long long)b * 1024 * 2048;
#pragma unroll
    for (int mi = 0; mi < 4; mi++) {
      unsigned short vals[4][4];
#pragma unroll
      for (int rr = 0; rr < 4; rr++) {
        const float b_ = bv[d0 + wm + mi * 16 + q4 * 4 + rr];  // bias per d-row
#pragma unroll
        for (int ni = 0; ni < 4; ni++)
          vals[ni][rr] = f2bf(acc[mi][ni][rr] + b_);
      }
      repack_store_mi(vals, sh, mi, d0, sloc, 2048, Outb);
    }
    return;
  }

  // ---- Q/K path: bias + RoPE (native sin/cos), per-mi repack ----
  const int m0 = (t >> 3) * 128;   // token rows
  const int n0 = (t & 7) * 128;    // feature cols
  const unsigned short* W = which == 0 ? Wq : Wk;
  const float* bias = which == 0 ? bq : bk;
  unsigned short* Out = which == 0 ? Q : Ko;

  core4h(xb + (long long)m0 * 1024, 1024, W + (long long)n0 * 1024, 1024, 32, acc, sh);
  __syncthreads();

  const float NEG_L2T_512 = -0.025952563239354392f;  // -log2(10000)/512
  const float INV2PI = 0.15915494309189535f;
  float freqn[4];
#pragma unroll
  for (int ni = 0; ni < 4; ni++) {
    int gn = n0 + wn + ni * 16 + cl;
    freqn[ni] = exp2f(NEG_L2T_512 * (float)(gn >> 1));
  }
#pragma unroll
  for (int mi = 0; mi < 4; mi++) {
    unsigned short vals[4][4];
    // batch-local time index (tiles never straddle batches; 2048 % 128 == 0)
    const int t0 = (m0 & 2047) + wm + mi * 16 + q4 * 4;
#pragma unroll
    for (int ni = 0; ni < 4; ni++) {
      const int gn = n0 + wn + ni * 16 + cl;
      const float bi = bias[gn];
#pragma unroll
      for (int rr = 0; rr < 4; rr++) {
        float v = acc[mi][ni][rr] + bi;
        float partner = __shfl_xor(v, 1, 64);
        float ang = (float)(t0 + rr) * freqn[ni];
        float rev = ang * INV2PI;
        rev = rev - floorf(rev);           // v_sin/v_cos domain
        float c_ = __builtin_amdgcn_cosf(rev);
        float s_ = __builtin_amdgcn_sinf(rev);
        v = v * c_ + ((gn & 1) ? partner : -partner) * s_;
        vals[ni][rr] = f2bf(v);
      }
    }
    repack_store_mi(vals, sh, mi, m0, n0, 1024, Out);
  }
}

// ---- P = exp(Q K^T / sqrt(C)) (causal-zeroed), bf16; row sums via atomics -
// Flat 544-block grid, XCD-chunked bijective remap (544 = 8*68).
__global__ __launch_bounds__(256, 2) void score_exp(const unsigned short* __restrict__ Q,
                                                    const unsigned short* __restrict__ Kk,
                                                    unsigned short* __restrict__ P,
                                                    float* __restrict__ row_sum) {
  __shared__ unsigned short sh[24576];   // 48 KiB: 3 GEMM bufs, then repack
  const int flat = blockIdx.x;                       // 0..543
  const int swz = (flat & 7) * 68 + (flat >> 3);     // bijective XCD chunking
  const int b = swz / 136;
  const int bx = swz % 136;
  int i = (int)((sqrtf(8.0f * (float)bx + 1.0f) - 1.0f) * 0.5f);
  while ((i + 1) * (i + 2) / 2 <= bx) ++i;
  while (i * (i + 1) / 2 > bx) --i;
  const int j = bx - i * (i + 1) / 2;       // 0..i
  const int m0 = i * 128, n0 = j * 128;
  const unsigned short* Qb = Q + (long long)b * 2048 * 1024;
  const unsigned short* Kb = Kk + (long long)b * 2048 * 1024;
  unsigned short* Pb = P + (long long)b * 2048 * 2048;
  float* rs = row_sum + b * 2048;

  f32x4 acc[4][4];
#pragma unroll
  for (int ii = 0; ii < 4; ii++)
#pragma unroll
    for (int jj = 0; jj < 4; jj++)
#pragma unroll
      for (int k = 0; k < 4; k++) acc[ii][jj][k] = 0.0f;

  core4h(Qb + (long long)m0 * 1024, 1024, Kb + (long long)n0 * 1024, 1024, 32, acc, sh);
  __syncthreads();

  const int tid = threadIdx.x, lane = tid & 63, w = tid >> 6;
  const int wm = (w & 1) << 6, wn = (w >> 1) << 6;
  const int cl = lane & 15, q4 = lane >> 4;
  const bool diag = (i == j);
#pragma unroll
  for (int mi = 0; mi < 4; mi++) {
    unsigned short vals[4][4];
    float rsum[4] = {0.f, 0.f, 0.f, 0.f};
#pragma unroll
    for (int ni = 0; ni < 4; ni++) {
      const int gn = n0 + wn + ni * 16 + cl;
#pragma unroll
      for (int rr = 0; rr < 4; rr++) {
        const int gm = m0 + wm + mi * 16 + q4 * 4 + rr;
        float e = (diag && gn > gm) ? 0.0f : __expf(acc[mi][ni][rr] * 0.03125f);
        vals[ni][rr] = f2bf(e);
        rsum[rr] += e;
      }
    }
#pragma unroll
    for (int rr = 0; rr < 4; rr++) {
#pragma unroll
      for (int off = 1; off < 16; off <<= 1) rsum[rr] += __shfl_xor(rsum[rr], off, 64);
    }
    if (cl == 0) {
      const int gm = m0 + wm + mi * 16 + q4 * 4;
#pragma unroll
      for (int rr = 0; rr < 4; rr++) atomicAdd(&rs[gm + rr], rsum[rr]);
    }
    repack_store_mi(vals, sh, mi, m0, n0, 2048, Pb);
  }
}

// ---- O = (P V) / row_sum -------------------------------------------------
// Flat 512-block grid, XCD-paired balanced decode (R17).
__global__ __launch_bounds__(256, 2) void pv_gemm(const unsigned short* __restrict__ P,
                                                  const unsigned short* __restrict__ Vt,
                                                  const float* __restrict__ row_sum,
                                                  unsigned short* __restrict__ O) {
  __shared__ unsigned short sh[24576];   // 48 KiB: 3 GEMM bufs, then repack
  const int p = blockIdx.x;          // 0..511
  const int xcd = p & 7;
  const int idx = p >> 3;            // 0..63
  const int g = idx >> 3;            // 0..7 (4 long groups, then 4 short)
  const int dt = idx & 7;            // d tile
  const int b  = (g < 4) ? g : g - 4;
  const int mt = (g < 4) ? 15 - xcd : xcd;
  const int m0 = mt * 128;           // t tile
  const int n0 = dt * 128;           // d tile
  const unsigned short* Pb = P + (long long)b * 2048 * 2048;
  const unsigned short* Vb = Vt + (long long)b * 1024 * 2048;
  const float* rs = row_sum + b * 2048;
  const int nkt = 4 * (mt + 1);      // K = m0+128 -> K/32, even >= 4

  f32x4 acc[4][4];
#pragma unroll
  for (int i = 0; i < 4; i++)
#pragma unroll
    for (int j = 0; j < 4; j++)
#pragma unroll
      for (int k = 0; k < 4; k++) acc[i][j][k] = 0.0f;

  core4h(Pb + (long long)m0 * 2048, 2048, Vb + (long long)n0 * 2048, 2048, nkt, acc, sh);
  __syncthreads();

  const int tid = threadIdx.x, lane = tid & 63, w = tid >> 6;
  const int wm = (w & 1) << 6;
  const int q4 = lane >> 4;
#pragma unroll
  for (int mi = 0; mi < 4; mi++) {
    unsigned short vals[4][4];
    float inv[4];
    const int gm0 = m0 + wm + mi * 16 + q4 * 4;
#pragma unroll
    for (int rr = 0; rr < 4; rr++) inv[rr] = 1.0f / rs[gm0 + rr];
#pragma unroll
    for (int ni = 0; ni < 4; ni++)
#pragma unroll
      for (int rr = 0; rr < 4; rr++)
        vals[ni][rr] = f2bf(acc[mi][ni][rr] * inv[rr]);
    repack_store_mi(vals, sh, mi, m0, n0, 1024, O + (long long)b * 2048 * 1024);
  }
}

// ---- out = O Wf^T + bf, fp32 out (core4, 512 thr) -------------------------
__global__ __launch_bounds__(512, 2) void final_gemm(const unsigned short* __restrict__ O,
                                                     const unsigned short* __restrict__ Wf,
                                                     const float* __restrict__ bf_,
                                                     float* __restrict__ out) {
  __shared__ unsigned short lds[49152];
  float* shf = (float*)lds;
  const int tid = threadIdx.x, lane = tid & 63, w = tid >> 6;
  const int wr = w >> 2, wc = w & 3;
  const int cl = lane & 15, q4 = lane >> 4;
  const int m0 = blockIdx.x * 128;
  const int n0 = blockIdx.y * 256;

  f32x4 acc[4][4];
#pragma unroll
  for (int i = 0; i < 4; i++)
#pragma unroll
    for (int j = 0; j < 4; j++)
#pragma unroll
      for (int k = 0; k < 4; k++) acc[i][j][k] = 0.0f;

  core4(O + (long long)m0 * 1024, 1024, Wf + (long long)n0 * 1024, 1024, 32, acc, lds);

  // fp32 repack in two 64-row rounds (64 x 260 floats = 66.5 KB <= 96 KB)
#pragma unroll
  for (int r = 0; r < 2; ++r) {
    __syncthreads();
    if (wr == r) {
#pragma unroll
      for (int mi = 0; mi < 4; ++mi)
#pragma unroll
        for (int nj = 0; nj < 4; ++nj) {
          const int col = wc * 64 + nj * 16 + cl;
          const float bi = bf_[n0 + col];
#pragma unroll
          for (int rr = 0; rr < 4; ++rr)
            shf[(mi * 16 + q4 * 4 + rr) * 260 + col] = acc[mi][nj][rr] + bi;
        }
    }
    __syncthreads();
#pragma unroll
    for (int it = 0; it < 8; ++it) {
      int c = it * 512 + tid;
      int row = c >> 6, c4 = (c & 63) << 2;
      float4 v = *(const float4*)(shf + row * 260 + c4);
      *(float4*)(out + (long long)(m0 + r * 64 + row) * 1024 + n0 + c4) = v;
    }
  }
}

// ---------------------------------------------------------------------------
extern "C" void kernel_launch(void* const* d_in, const int* in_sizes, int n_in,
                              void* d_out, int out_size, void* d_ws, size_t ws_size,
                              hipStream_t stream) {
  (void)in_sizes; (void)n_in; (void)out_size; (void)ws_size;
  const float* x   = (const float*)d_in[0];
  const float* Wq  = (const float*)d_in[1];
  const float* bq  = (const float*)d_in[2];
  const float* Wk  = (const float*)d_in[3];
  const float* bk  = (const float*)d_in[4];
  const float* Wv  = (const float*)d_in[5];
  const float* bv  = (const float*)d_in[6];
  const float* Wf  = (const float*)d_in[7];
  const float* bf_ = (const float*)d_in[8];
  float* out = (float*)d_out;

  char* ws = (char*)d_ws;
  const size_t MB = 1024 * 1024;
  unsigned short* xb  = (unsigned short*)(ws);             // 16 MB
  unsigned short* Wqb = (unsigned short*)(ws + 16 * MB);   // 2 MB
  unsigned short* Wkb = (unsigned short*)(ws + 18 * MB);   // 2 MB
  unsigned short* Wvb = (unsigned short*)(ws + 20 * MB);   // 2 MB
  unsigned short* Wfb = (unsigned short*)(ws + 22 * MB);   // 2 MB
  unsigned short* Qb  = (unsigned short*)(ws + 24 * MB);   // 16 MB
  unsigned short* Kb  = (unsigned short*)(ws + 40 * MB);   // 16 MB
  unsigned short* Vtb = (unsigned short*)(ws + 56 * MB);   // 16 MB
  unsigned short* Ob  = (unsigned short*)(ws + 72 * MB);   // 16 MB
  unsigned short* Pb  = (unsigned short*)(ws + 88 * MB);   // 32 MB P bf16
  float*          rsum= (float*)(ws + 120 * MB);           // 32 KB row sums

  cast_all<<<dim3(3145728 / 256), dim3(256), 0, stream>>>(x, Wq, Wk, Wv, Wf, xb, Wqb, Wkb, Wvb, Wfb, rsum);
  proj_rope<<<dim3(1536), dim3(256), 0, stream>>>(xb, Wqb, Wkb, Wvb, bq, bk, bv, Qb, Kb, Vtb);
  score_exp<<<dim3(544), dim3(256), 0, stream>>>(Qb, Kb, Pb, rsum);
  pv_gemm<<<dim3(512), dim3(256), 0, stream>>>(Pb, Vtb, rsum, Ob);
  final_gemm<<<dim3(64, 4), dim3(512), 0, stream>>>(Ob, Wfb, bf_, out);
}

// Round 12
// 262.875 us; speedup vs baseline: 1.6814x; 1.0493x over previous
//
#include <hip/hip_runtime.h>
#include <math.h>

// ---------------------------------------------------------------------------
// MultiChannelAttention on MI355X (gfx950)
// out = softmax(causal(rope(xWq^T) rope(xWk^T)^T / sqrt(C))) (xWv^T) Wf^T + b
// B=4 T=2048 C=1024. bf16 MFMA (16x16x32), fp32 accum.
// R20 (FINAL/lock-in): exact R17 configuration -- the session's best
//      measured point (271.0us). R19 falsified the occupancy theory for
//      proj (3 blk/CU == 1 blk/CU == ~77us), and R9-R13 falsified four
//      schedule variants; proj ~77us is this core family's plateau.
//      Budget at plateau: cast 12 (BW roofline) + proj 77 + score ~38 +
//      pv ~38 + final ~27 + harness fills ~80 = 272 = measured.
// R17: pv XCD-paired balanced grid. R16: score 3-buf ring + XCD-chunked
//      grid. R11: core4 pipeline (reg-dbuf fragments, counted vmcnt).
// R8: V projection computes Vt natively. R7: triangular score grid.
// R5: native v_sin/v_cos RoPE. R2: fused exp-softmax (P=exp(s), atomics).
// Workspace layout (121 MB):
//   [0,16) xb  [16,24) Wq/Wk/Wv/Wf bf16  [24,40) Q  [40,56) K
//   [56,72) Vt  [72,88) O  [88,120) P bf16  [120,+32K) row_sum
// ---------------------------------------------------------------------------

#define AS1(p) ((__attribute__((address_space(1))) void*)(p))
#define AS3(p) ((__attribute__((address_space(3))) void*)(p))

typedef __attribute__((ext_vector_type(8))) short bf16x8;
typedef __attribute__((ext_vector_type(4))) float f32x4;

__device__ __forceinline__ unsigned short f2bf(float f) {
  unsigned int u = __float_as_uint(f);
  u += 0x7fffu + ((u >> 16) & 1u);   // round-to-nearest-even
  return (unsigned short)(u >> 16);
}

// ---- fp32 -> bf16 cast for x + 4 weight matrices, + rsum zero, one launch -
__global__ __launch_bounds__(256) void cast_all(
    const float* __restrict__ x, const float* __restrict__ Wq,
    const float* __restrict__ Wk, const float* __restrict__ Wv,
    const float* __restrict__ Wf,
    unsigned short* __restrict__ xb, unsigned short* __restrict__ Wqb,
    unsigned short* __restrict__ Wkb, unsigned short* __restrict__ Wvb,
    unsigned short* __restrict__ Wfb, float* __restrict__ rsum) {
  int i = blockIdx.x * 256 + threadIdx.x;           // float4 index
  if (i < 8192) rsum[i] = 0.0f;                     // fused memset (32 KB)
  const float* src; unsigned short* dst; int off;
  if (i < 2097152) { src = x; dst = xb; off = i; }
  else {
    int j = i - 2097152;
    int w = j >> 18; off = j & 262143;              // 262144 float4 per W
    src = (w == 0) ? Wq : (w == 1) ? Wk : (w == 2) ? Wv : Wf;
    dst = (w == 0) ? Wqb : (w == 1) ? Wkb : (w == 2) ? Wvb : Wfb;
  }
  float4 f = ((const float4*)src)[off];
  ushort4 o;
  o.x = f2bf(f.x); o.y = f2bf(f.y); o.z = f2bf(f.z); o.w = f2bf(f.w);
  ((ushort4*)dst)[off] = o;
}

// ---- LDS repack + coalesced bf16x8 store of one mi-slice (256 thr) --------
__device__ __forceinline__ void repack_store_mi(unsigned short (&vals)[4][4],
                                                unsigned short* sh, int mi,
                                                int m0, int n0, long long ldo,
                                                unsigned short* __restrict__ Out) {
  const int tid = threadIdx.x, lane = tid & 63, w = tid >> 6;
  const int half = w & 1, wn = (w >> 1) << 6;
  const int cl = lane & 15, q4 = lane >> 4;
  const int lr = half * 16 + q4 * 4;
#pragma unroll
  for (int ni = 0; ni < 4; ni++)
#pragma unroll
    for (int rr = 0; rr < 4; rr++)
      sh[(lr + rr) * 132 + wn + ni * 16 + cl] = vals[ni][rr];
  __syncthreads();
#pragma unroll
  for (int it = 0; it < 2; ++it) {
    int row = (tid >> 4) + it * 16;          // 0..31
    int c8 = (tid & 15) << 3;                // 0..120
    bf16x8 v = *(const bf16x8*)(sh + row * 132 + c8);
    int gr = m0 + (row < 16 ? mi * 16 + row : 48 + mi * 16 + row);
    *(bf16x8*)(Out + (long long)gr * ldo + n0 + c8) = v;
  }
  __syncthreads();
}

// ---------------------------------------------------------------------------
// core4 (proj/final): 128x256 tile, 512 thr = 8 waves (2M x 4N), per-wave
// 64x64 (acc[4][4]). BK=32; 4 LDS buffers of 24 KiB; 3-deep global prefetch
// (vmcnt(6) certify); reg-dbuf fragments. 2 barriers/K-tile. 16B chunks
// swizzled c ^= (row>>1)&3, pre-swizzled global source, linear LDS dest.
// C[m,n] = sum_k A[m,k]*B[n,k], A/B bf16 K-fast. nkt even >= 4.
// ---------------------------------------------------------------------------
__device__ __forceinline__ void core4(
    const unsigned short* __restrict__ A, long long lda,
    const unsigned short* __restrict__ B, long long ldb,
    int nkt, f32x4 (&acc)[4][4], unsigned short* lds) {
  const int tid  = threadIdx.x;
  const int lane = tid & 63;
  const int w    = tid >> 6;
  const int wr   = w >> 2;            // 0..1
  const int wc   = w & 3;             // 0..3
  const int fr   = lane & 15;
  const int fq   = lane >> 4;
  const int csel = (fq ^ ((fr >> 1) & 3)) << 3;   // fragment chunk swizzle
  const int srow = tid >> 2;                      // staging row 0..127
  const int scsw = ((tid & 3) ^ ((srow >> 1) & 3)) << 3;
  const unsigned short* Asrc  = A + (long long)srow * lda + scsw;
  const unsigned short* Bsrc0 = B + (long long)srow * ldb + scsw;
  const unsigned short* Bsrc1 = B + (long long)(srow + 128) * ldb + scsw;
  unsigned short* dsta = lds + tid * 8;           // per-thread 16B slot

  auto stage = [&](int kt) {
    const int bo = (kt & 3) * 12288;
    const long long ko = (long long)kt * 32;
    __builtin_amdgcn_global_load_lds(AS1(Asrc + ko),  AS3(dsta + bo),        16, 0, 0);
    __builtin_amdgcn_global_load_lds(AS1(Bsrc0 + ko), AS3(dsta + bo + 4096), 16, 0, 0);
    __builtin_amdgcn_global_load_lds(AS1(Bsrc1 + ko), AS3(dsta + bo + 8192), 16, 0, 0);
  };
  auto rdfrag = [&](int kt, bf16x8 (&r)[8]) {
    const unsigned short* Ab = lds + (kt & 3) * 12288 + (wr * 64 + fr) * 32 + csel;
    const unsigned short* Bb = lds + (kt & 3) * 12288 + 4096 + (wc * 64 + fr) * 32 + csel;
#pragma unroll
    for (int mi = 0; mi < 4; ++mi) r[mi] = *(const bf16x8*)(Ab + mi * 512);
#pragma unroll
    for (int nj = 0; nj < 4; ++nj) r[4 + nj] = *(const bf16x8*)(Bb + nj * 512);
  };

  bf16x8 ra[8], rb[8];
  stage(0); stage(1); stage(2);
  asm volatile("s_waitcnt vmcnt(6)" ::: "memory");
  __builtin_amdgcn_s_barrier();
  rdfrag(0, ra);

  auto body = [&](int kt, bf16x8 (&cur)[8], bf16x8 (&nxt)[8]) {
    if (kt + 3 < nkt) {
      stage(kt + 3);
      asm volatile("s_waitcnt vmcnt(6)" ::: "memory");
    } else if (kt + 2 < nkt) {
      asm volatile("s_waitcnt vmcnt(3)" ::: "memory");
    } else if (kt + 1 < nkt) {
      asm volatile("s_waitcnt vmcnt(0)" ::: "memory");
    }
    if (kt + 1 < nkt) {
      __builtin_amdgcn_s_barrier();
      rdfrag(kt + 1, nxt);
    }
    __builtin_amdgcn_s_setprio(1);
#pragma unroll
    for (int mi = 0; mi < 4; ++mi)
#pragma unroll
      for (int nj = 0; nj < 4; ++nj)
        acc[mi][nj] = __builtin_amdgcn_mfma_f32_16x16x32_bf16(cur[mi], cur[4 + nj], acc[mi][nj], 0, 0, 0);
    __builtin_amdgcn_s_setprio(0);
    if (kt + 1 < nkt) __builtin_amdgcn_s_barrier();
  };

#pragma unroll 1
  for (int kt = 0; kt < nkt; kt += 2) {
    body(kt, ra, rb);
    body(kt + 1, rb, ra);
  }
}

// ---------------------------------------------------------------------------
// core4h (score/pv): 256 thr / 128x128 tile, 4 waves (2M x 2N), per-wave
// 64x64 (acc[4][4]). BK=32; 3 LDS buffers of 16 KiB = 48 KiB -> 3 blocks/CU.
// Depth-2 prefetch: stage(kt+2) in body, gate vmcnt(4) certifies tile kt+1.
// Reg-dbuf fragments; 2 barriers/K-tile. WAR ledger: stage(kt+2) overwrites
// buf[(kt-1)%3], whose rdfrag(kt-1) reads were consumed by MFMA at iter kt-1
// before its trailing barrier. nkt even >= 2.
// ---------------------------------------------------------------------------
__device__ __forceinline__ void core4h(
    const unsigned short* __restrict__ A, long long lda,
    const unsigned short* __restrict__ B, long long ldb,
    int nkt, f32x4 (&acc)[4][4], unsigned short* lds) {
  const int tid  = threadIdx.x;          // 0..255
  const int lane = tid & 63;
  const int w    = tid >> 6;             // 0..3
  const int wm   = (w & 1) << 6;         // M half
  const int wn   = (w >> 1) << 6;        // N half
  const int fr   = lane & 15;
  const int fq   = lane >> 4;
  const int csel = (fq ^ ((fr >> 1) & 3)) << 3;
  const int srow = tid >> 2;             // 0..63
  const int scsw = ((tid & 3) ^ ((srow >> 1) & 3)) << 3;
  const unsigned short* Asrc0 = A + (long long)srow * lda + scsw;
  const unsigned short* Asrc1 = A + (long long)(srow + 64) * lda + scsw;
  const unsigned short* Bsrc0 = B + (long long)srow * ldb + scsw;
  const unsigned short* Bsrc1 = B + (long long)(srow + 64) * ldb + scsw;
  unsigned short* dsta = lds + tid * 8;  // 16B per thread per instr

  auto stage = [&](int kt) {
    const int bo = (kt % 3) * 8192;
    const long long ko = (long long)kt * 32;
    __builtin_amdgcn_global_load_lds(AS1(Asrc0 + ko), AS3(dsta + bo),        16, 0, 0);
    __builtin_amdgcn_global_load_lds(AS1(Asrc1 + ko), AS3(dsta + bo + 2048), 16, 0, 0);
    __builtin_amdgcn_global_load_lds(AS1(Bsrc0 + ko), AS3(dsta + bo + 4096), 16, 0, 0);
    __builtin_amdgcn_global_load_lds(AS1(Bsrc1 + ko), AS3(dsta + bo + 6144), 16, 0, 0);
  };
  auto rdfrag = [&](int kt, bf16x8 (&r)[8]) {
    const unsigned short* Ab = lds + (kt % 3) * 8192 + (wm + fr) * 32 + csel;
    const unsigned short* Bb = lds + (kt % 3) * 8192 + 4096 + (wn + fr) * 32 + csel;
#pragma unroll
    for (int mi = 0; mi < 4; ++mi) r[mi] = *(const bf16x8*)(Ab + mi * 512);
#pragma unroll
    for (int nj = 0; nj < 4; ++nj) r[4 + nj] = *(const bf16x8*)(Bb + nj * 512);
  };

  bf16x8 ra[8], rb[8];
  stage(0); stage(1);
  asm volatile("s_waitcnt vmcnt(4)" ::: "memory");   // tile 0 landed
  __builtin_amdgcn_s_barrier();
  rdfrag(0, ra);

  auto body = [&](int kt, bf16x8 (&cur)[8], bf16x8 (&nxt)[8]) {
    if (kt + 2 < nkt) {
      stage(kt + 2);
      asm volatile("s_waitcnt vmcnt(4)" ::: "memory");   // tile kt+1 landed
    } else if (kt + 1 < nkt) {
      asm volatile("s_waitcnt vmcnt(0)" ::: "memory");
    }
    if (kt + 1 < nkt) {
      __builtin_amdgcn_s_barrier();
      rdfrag(kt + 1, nxt);
    }
    __builtin_amdgcn_s_setprio(1);
#pragma unroll
    for (int mi = 0; mi < 4; ++mi)
#pragma unroll
      for (int nj = 0; nj < 4; ++nj)
        acc[mi][nj] = __builtin_amdgcn_mfma_f32_16x16x32_bf16(cur[mi], cur[4 + nj], acc[mi][nj], 0, 0, 0);
    __builtin_amdgcn_s_setprio(0);
    if (kt + 1 < nkt) __builtin_amdgcn_s_barrier();
  };

#pragma unroll 1
  for (int kt = 0; kt < nkt; kt += 2) {
    body(kt, ra, rb);
    body(kt + 1, rb, ra);
  }
}

// ---- Q/K/V projections; Q/K get RoPE; V computed AS Vt (swapped operands) -
// Grid (64, 4, 3), 512 threads.
__global__ __launch_bounds__(512, 2) void proj_rope(
    const unsigned short* __restrict__ xb,
    const unsigned short* __restrict__ Wq, const unsigned short* __restrict__ Wk,
    const unsigned short* __restrict__ Wv,
    const float* __restrict__ bq, const float* __restrict__ bk, const float* __restrict__ bv,
    unsigned short* __restrict__ Q, unsigned short* __restrict__ Ko,
    unsigned short* __restrict__ Vt) {
  __shared__ unsigned short lds[49152];   // 96 KiB: GEMM 4-buf, then repack
  const int which = blockIdx.z;
  const int tid = threadIdx.x, lane = tid & 63, w = tid >> 6;
  const int wr = w >> 2, wc = w & 3;
  const int cl = lane & 15, q4 = lane >> 4;

  f32x4 acc[4][4];
#pragma unroll
  for (int i = 0; i < 4; i++)
#pragma unroll
    for (int j = 0; j < 4; j++)
#pragma unroll
      for (int k = 0; k < 4; k++) acc[i][j][k] = 0.0f;

  if (which == 2) {
    // ---- V path: Vt[d,s] = sum_k Wv[d,k] x[s,k]; A = Wv (m=d), B = x (n=s)
    const int p = blockIdx.x + 64 * blockIdx.y;     // physical 0..255
    const int m0 = ((p >> 3) & 7) * 128;            // d tile
    const int n0 = (4 * (p & 7) + (p >> 6)) * 256;  // global s tile (XCD remap)
    core4(Wv + (long long)m0 * 1024, 1024, xb + (long long)n0 * 1024, 1024, 32, acc, lds);
    __syncthreads();
    const int b = n0 >> 11, sloc = n0 & 2047;
#pragma unroll
    for (int mi = 0; mi < 4; ++mi) {
      const int lr = wr * 64 + mi * 16 + q4 * 4;
#pragma unroll
      for (int rr = 0; rr < 4; ++rr) {
        const float b_ = bv[m0 + lr + rr];          // bias per d-row
#pragma unroll
        for (int nj = 0; nj < 4; ++nj)
          lds[(lr + rr) * 264 + wc * 64 + nj * 16 + cl] = f2bf(acc[mi][nj][rr] + b_);
      }
    }
    __syncthreads();
    unsigned short* Outb = Vt + (long long)b * 1024 * 2048;
#pragma unroll
    for (int it = 0; it < 8; ++it) {
      int c = it * 512 + tid;
      int row = c >> 5, c8 = (c & 31) << 3;
      bf16x8 v = *(const bf16x8*)(lds + row * 264 + c8);
      *(bf16x8*)(Outb + (long long)(m0 + row) * 2048 + sloc + c8) = v;
    }
    return;
  }

  // ---- Q/K path: bias + RoPE (native sin/cos) ----
  const int m0 = blockIdx.x * 128;    // token rows
  const int n0 = blockIdx.y * 256;    // feature cols
  const unsigned short* W = which == 0 ? Wq : Wk;
  const float* bias = which == 0 ? bq : bk;
  unsigned short* Out = which == 0 ? Q : Ko;

  core4(xb + (long long)m0 * 1024, 1024, W + (long long)n0 * 1024, 1024, 32, acc, lds);
  __syncthreads();

  const float NEG_L2T_512 = -0.025952563239354392f;  // -log2(10000)/512
  const float INV2PI = 0.15915494309189535f;
  float freqn[4];
#pragma unroll
  for (int nj = 0; nj < 4; ++nj) {
    int gn = n0 + wc * 64 + nj * 16 + cl;
    freqn[nj] = exp2f(NEG_L2T_512 * (float)(gn >> 1));
  }
#pragma unroll
  for (int mi = 0; mi < 4; ++mi) {
    const int lr = wr * 64 + mi * 16 + q4 * 4;
    const int t0 = (m0 & 2047) + lr;   // batch-local time (tiles never straddle)
#pragma unroll
    for (int nj = 0; nj < 4; ++nj) {
      const int gn = n0 + wc * 64 + nj * 16 + cl;
      const float bi = bias[gn];
#pragma unroll
      for (int rr = 0; rr < 4; ++rr) {
        float v = acc[mi][nj][rr] + bi;
        float partner = __shfl_xor(v, 1, 64);
        float ang = (float)(t0 + rr) * freqn[nj];
        float rev = ang * INV2PI;
        rev = rev - floorf(rev);           // v_sin/v_cos domain
        float c_ = __builtin_amdgcn_cosf(rev);
        float s_ = __builtin_amdgcn_sinf(rev);
        v = v * c_ + ((gn & 1) ? partner : -partner) * s_;
        lds[(lr + rr) * 264 + wc * 64 + nj * 16 + cl] = f2bf(v);
      }
    }
  }
  __syncthreads();
#pragma unroll
  for (int it = 0; it < 8; ++it) {
    int c = it * 512 + tid;
    int row = c >> 5, c8 = (c & 31) << 3;
    bf16x8 v = *(const bf16x8*)(lds + row * 264 + c8);
    *(bf16x8*)(Out + (long long)(m0 + row) * 1024 + n0 + c8) = v;
  }
}

// ---- P = exp(Q K^T / sqrt(C)) (causal-zeroed), bf16; row sums via atomics -
// Flat 544-block grid, XCD-chunked bijective remap (544 = 8*68).
__global__ __launch_bounds__(256, 2) void score_exp(const unsigned short* __restrict__ Q,
                                                    const unsigned short* __restrict__ Kk,
                                                    unsigned short* __restrict__ P,
                                                    float* __restrict__ row_sum) {
  __shared__ unsigned short sh[24576];   // 48 KiB: 3 GEMM bufs, then repack
  const int flat = blockIdx.x;                       // 0..543
  const int swz = (flat & 7) * 68 + (flat >> 3);     // bijective XCD chunking
  const int b = swz / 136;
  const int bx = swz % 136;
  int i = (int)((sqrtf(8.0f * (float)bx + 1.0f) - 1.0f) * 0.5f);
  while ((i + 1) * (i + 2) / 2 <= bx) ++i;
  while (i * (i + 1) / 2 > bx) --i;
  const int j = bx - i * (i + 1) / 2;       // 0..i
  const int m0 = i * 128, n0 = j * 128;
  const unsigned short* Qb = Q + (long long)b * 2048 * 1024;
  const unsigned short* Kb = Kk + (long long)b * 2048 * 1024;
  unsigned short* Pb = P + (long long)b * 2048 * 2048;
  float* rs = row_sum + b * 2048;

  f32x4 acc[4][4];
#pragma unroll
  for (int ii = 0; ii < 4; ii++)
#pragma unroll
    for (int jj = 0; jj < 4; jj++)
#pragma unroll
      for (int k = 0; k < 4; k++) acc[ii][jj][k] = 0.0f;

  core4h(Qb + (long long)m0 * 1024, 1024, Kb + (long long)n0 * 1024, 1024, 32, acc, sh);
  __syncthreads();

  const int tid = threadIdx.x, lane = tid & 63, w = tid >> 6;
  const int wm = (w & 1) << 6, wn = (w >> 1) << 6;
  const int cl = lane & 15, q4 = lane >> 4;
  const bool diag = (i == j);
#pragma unroll
  for (int mi = 0; mi < 4; mi++) {
    unsigned short vals[4][4];
    float rsum[4] = {0.f, 0.f, 0.f, 0.f};
#pragma unroll
    for (int ni = 0; ni < 4; ni++) {
      const int gn = n0 + wn + ni * 16 + cl;
#pragma unroll
      for (int rr = 0; rr < 4; rr++) {
        const int gm = m0 + wm + mi * 16 + q4 * 4 + rr;
        float e = (diag && gn > gm) ? 0.0f : __expf(acc[mi][ni][rr] * 0.03125f);
        vals[ni][rr] = f2bf(e);
        rsum[rr] += e;
      }
    }
#pragma unroll
    for (int rr = 0; rr < 4; rr++) {
#pragma unroll
      for (int off = 1; off < 16; off <<= 1) rsum[rr] += __shfl_xor(rsum[rr], off, 64);
    }
    if (cl == 0) {
      const int gm = m0 + wm + mi * 16 + q4 * 4;
#pragma unroll
      for (int rr = 0; rr < 4; rr++) atomicAdd(&rs[gm + rr], rsum[rr]);
    }
    repack_store_mi(vals, sh, mi, m0, n0, 2048, Pb);
  }
}

// ---- O = (P V) / row_sum -------------------------------------------------
// Flat 512-block grid, XCD-paired balanced decode (R17).
__global__ __launch_bounds__(256, 2) void pv_gemm(const unsigned short* __restrict__ P,
                                                  const unsigned short* __restrict__ Vt,
                                                  const float* __restrict__ row_sum,
                                                  unsigned short* __restrict__ O) {
  __shared__ unsigned short sh[24576];   // 48 KiB: 3 GEMM bufs, then repack
  const int p = blockIdx.x;          // 0..511
  const int xcd = p & 7;
  const int idx = p >> 3;            // 0..63
  const int g = idx >> 3;            // 0..7 (4 long groups, then 4 short)
  const int dt = idx & 7;            // d tile
  const int b  = (g < 4) ? g : g - 4;
  const int mt = (g < 4) ? 15 - xcd : xcd;
  const int m0 = mt * 128;           // t tile
  const int n0 = dt * 128;           // d tile
  const unsigned short* Pb = P + (long long)b * 2048 * 2048;
  const unsigned short* Vb = Vt + (long long)b * 1024 * 2048;
  const float* rs = row_sum + b * 2048;
  const int nkt = 4 * (mt + 1);      // K = m0+128 -> K/32, even >= 4

  f32x4 acc[4][4];
#pragma unroll
  for (int i = 0; i < 4; i++)
#pragma unroll
    for (int j = 0; j < 4; j++)
#pragma unroll
      for (int k = 0; k < 4; k++) acc[i][j][k] = 0.0f;

  core4h(Pb + (long long)m0 * 2048, 2048, Vb + (long long)n0 * 2048, 2048, nkt, acc, sh);
  __syncthreads();

  const int tid = threadIdx.x, lane = tid & 63, w = tid >> 6;
  const int wm = (w & 1) << 6;
  const int q4 = lane >> 4;
#pragma unroll
  for (int mi = 0; mi < 4; mi++) {
    unsigned short vals[4][4];
    float inv[4];
    const int gm0 = m0 + wm + mi * 16 + q4 * 4;
#pragma unroll
    for (int rr = 0; rr < 4; rr++) inv[rr] = 1.0f / rs[gm0 + rr];
#pragma unroll
    for (int ni = 0; ni < 4; ni++)
#pragma unroll
      for (int rr = 0; rr < 4; rr++)
        vals[ni][rr] = f2bf(acc[mi][ni][rr] * inv[rr]);
    repack_store_mi(vals, sh, mi, m0, n0, 1024, O + (long long)b * 2048 * 1024);
  }
}

// ---- out = O Wf^T + bf, fp32 out (core4, 512 thr) -------------------------
__global__ __launch_bounds__(512, 2) void final_gemm(const unsigned short* __restrict__ O,
                                                     const unsigned short* __restrict__ Wf,
                                                     const float* __restrict__ bf_,
                                                     float* __restrict__ out) {
  __shared__ unsigned short lds[49152];
  float* shf = (float*)lds;
  const int tid = threadIdx.x, lane = tid & 63, w = tid >> 6;
  const int wr = w >> 2, wc = w & 3;
  const int cl = lane & 15, q4 = lane >> 4;
  const int m0 = blockIdx.x * 128;
  const int n0 = blockIdx.y * 256;

  f32x4 acc[4][4];
#pragma unroll
  for (int i = 0; i < 4; i++)
#pragma unroll
    for (int j = 0; j < 4; j++)
#pragma unroll
      for (int k = 0; k < 4; k++) acc[i][j][k] = 0.0f;

  core4(O + (long long)m0 * 1024, 1024, Wf + (long long)n0 * 1024, 1024, 32, acc, lds);

  // fp32 repack in two 64-row rounds (64 x 260 floats = 66.5 KB <= 96 KB)
#pragma unroll
  for (int r = 0; r < 2; ++r) {
    __syncthreads();
    if (wr == r) {
#pragma unroll
      for (int mi = 0; mi < 4; ++mi)
#pragma unroll
        for (int nj = 0; nj < 4; ++nj) {
          const int col = wc * 64 + nj * 16 + cl;
          const float bi = bf_[n0 + col];
#pragma unroll
          for (int rr = 0; rr < 4; ++rr)
            shf[(mi * 16 + q4 * 4 + rr) * 260 + col] = acc[mi][nj][rr] + bi;
        }
    }
    __syncthreads();
#pragma unroll
    for (int it = 0; it < 8; ++it) {
      int c = it * 512 + tid;
      int row = c >> 6, c4 = (c & 63) << 2;
      float4 v = *(const float4*)(shf + row * 260 + c4);
      *(float4*)(out + (long long)(m0 + r * 64 + row) * 1024 + n0 + c4) = v;
    }
  }
}

// ---------------------------------------------------------------------------
extern "C" void kernel_launch(void* const* d_in, const int* in_sizes, int n_in,
                              void* d_out, int out_size, void* d_ws, size_t ws_size,
                              hipStream_t stream) {
  (void)in_sizes; (void)n_in; (void)out_size; (void)ws_size;
  const float* x   = (const float*)d_in[0];
  const float* Wq  = (const float*)d_in[1];
  const float* bq  = (const float*)d_in[2];
  const float* Wk  = (const float*)d_in[3];
  const float* bk  = (const float*)d_in[4];
  const float* Wv  = (const float*)d_in[5];
  const float* bv  = (const float*)d_in[6];
  const float* Wf  = (const float*)d_in[7];
  const float* bf_ = (const float*)d_in[8];
  float* out = (float*)d_out;

  char* ws = (char*)d_ws;
  const size_t MB = 1024 * 1024;
  unsigned short* xb  = (unsigned short*)(ws);             // 16 MB
  unsigned short* Wqb = (unsigned short*)(ws + 16 * MB);   // 2 MB
  unsigned short* Wkb = (unsigned short*)(ws + 18 * MB);   // 2 MB
  unsigned short* Wvb = (unsigned short*)(ws + 20 * MB);   // 2 MB
  unsigned short* Wfb = (unsigned short*)(ws + 22 * MB);   // 2 MB
  unsigned short* Qb  = (unsigned short*)(ws + 24 * MB);   // 16 MB
  unsigned short* Kb  = (unsigned short*)(ws + 40 * MB);   // 16 MB
  unsigned short* Vtb = (unsigned short*)(ws + 56 * MB);   // 16 MB
  unsigned short* Ob  = (unsigned short*)(ws + 72 * MB);   // 16 MB
  unsigned short* Pb  = (unsigned short*)(ws + 88 * MB);   // 32 MB P bf16
  float*          rsum= (float*)(ws + 120 * MB);           // 32 KB row sums

  cast_all<<<dim3(3145728 / 256), dim3(256), 0, stream>>>(x, Wq, Wk, Wv, Wf, xb, Wqb, Wkb, Wvb, Wfb, rsum);
  proj_rope<<<dim3(64, 4, 3), dim3(512), 0, stream>>>(xb, Wqb, Wkb, Wvb, bq, bk, bv, Qb, Kb, Vtb);
  score_exp<<<dim3(544), dim3(256), 0, stream>>>(Qb, Kb, Pb, rsum);
  pv_gemm<<<dim3(512), dim3(256), 0, stream>>>(Pb, Vtb, rsum, Ob);
  final_gemm<<<dim3(64, 4), dim3(512), 0, stream>>>(Ob, Wfb, bf_, out);
}